// Round 6
// baseline (144.851 us; speedup 1.0000x reference)
//
#include <hip/hip_runtime.h>
#include <stdint.h>
#include <limits.h>

// Problem constants (match reference)
constexpr int BB      = 4;
constexpr int NN      = 8192;
constexpr int NPOINT  = 2048;
constexpr int CC      = 64;
constexpr int NSAMPLE = 32;
constexpr int KTOT    = NSAMPLE + 1;   // fps_idx prepended -> 33
constexpr int NCH     = 3 + 3 + CC;    // 70 output channels

// Spatial grid: 5x5x5 cells of 0.2 over [0,1]^3. Ball radius 0.1 spans <=3
// cells/axis (only when a padded bound straddles 2 boundaries; usually 2).
constexpr int   GG     = 5;
constexpr int   NCELL  = GG * GG * GG;        // 125
constexpr float RPADF  = 0.1001f;             // conservative cell-range radius
constexpr int   CAND_CAP = 192;               // in-ball count ~Poisson(34); +27 sigma

__device__ __forceinline__ int cell_of(float x, float y, float z) {
    int ix = (int)floorf(x * 5.0f); ix = ix < 0 ? 0 : (ix > 4 ? 4 : ix);
    int iy = (int)floorf(y * 5.0f); iy = iy < 0 ? 0 : (iy > 4 ? 4 : iy);
    int iz = (int)floorf(z * 5.0f); iz = iz < 0 ? 0 : (iz > 4 ? 4 : iz);
    return (ix * GG + iy) * GG + iz;
}

// ---------------------------------------------------------------------------
// Grid build kernel A: histogram points into per-batch cell counts.
// ---------------------------------------------------------------------------
__global__ __launch_bounds__(256) void hist_kernel(
    const float* __restrict__ xyz, int* __restrict__ cellcnt)
{
    const int t = blockIdx.x * 256 + threadIdx.x;
    if (t >= BB * NN) return;
    const int b = t >> 13;
    const float* p = xyz + (size_t)t * 3;
    const int c = cell_of(p[0], p[1], p[2]);
    atomicAdd(&cellcnt[b * NCELL + c], 1);
}

// ---------------------------------------------------------------------------
// Grid build kernel B: exclusive scan of 125 counts per batch -> cellstart
// (126 entries per batch). One wave per batch.
// ---------------------------------------------------------------------------
__global__ __launch_bounds__(256) void scan_kernel(
    const int* __restrict__ cellcnt, int* __restrict__ cellstart)
{
    const int w    = threadIdx.x >> 6;   // batch
    const int lane = threadIdx.x & 63;
    const int* cnt = cellcnt + w * NCELL;
    int x0 = (lane < NCELL) ? cnt[lane] : 0;                 // cells 0..63
    int x1 = (lane + 64 < NCELL) ? cnt[lane + 64] : 0;       // cells 64..124
#pragma unroll
    for (int d = 1; d < 64; d <<= 1) {
        int t0 = __shfl_up(x0, d);
        int t1 = __shfl_up(x1, d);
        if (lane >= d) { x0 += t0; x1 += t1; }
    }
    x1 += __shfl(x0, 63);
    int* cs = cellstart + w * (NCELL + 1);
    if (lane == 0) cs[0] = 0;
    cs[1 + lane] = x0;                        // positions 1..64
    if (lane <= 60) cs[65 + lane] = x1;       // positions 65..125
}

// ---------------------------------------------------------------------------
// Grid build kernel C: scatter points into cell-sorted SoA arrays
// (sx, sy, sz float; sidx original index). Order within a cell is arbitrary
// (atomics) — the rank-select in ball_query_grid restores index order.
// ---------------------------------------------------------------------------
__global__ __launch_bounds__(256) void scatter_kernel(
    const float* __restrict__ xyz, const int* __restrict__ cellstart,
    int* __restrict__ cursor,
    float* __restrict__ sx, float* __restrict__ sy, float* __restrict__ sz,
    int* __restrict__ sidx)
{
    const int t = blockIdx.x * 256 + threadIdx.x;
    if (t >= BB * NN) return;
    const int b = t >> 13;
    const int n = t & (NN - 1);
    const float* p = xyz + (size_t)t * 3;
    const float x = p[0], y = p[1], z = p[2];
    const int c = cell_of(x, y, z);
    const int pos = cellstart[b * (NCELL + 1) + c] + atomicAdd(&cursor[b * NCELL + c], 1);
    const int g = b * NN + pos;
    sx[g] = x; sy[g] = y; sz[g] = z; sidx[g] = n;
}

// ---------------------------------------------------------------------------
// Kernel 1: grid ball query. One wave per centroid. Walks the <=3x3 xy
// neighbor cell columns (z-runs contiguous in cell-major order), tests the
// exact d2 < r2 (same __f*_rn chain as numpy fp32 -> bit-exact), compacts
// all in-radius original indices into a per-wave LDS buffer, then
// rank-selects: rank r<32 writes out[1+r] (= first 32 in ascending index
// order); pad = wave-min (= first in-radius index); slot 0 = fps_idx.
// ---------------------------------------------------------------------------
__global__ __launch_bounds__(256) void ball_query_grid(
    const float* __restrict__ sx, const float* __restrict__ sy,
    const float* __restrict__ sz, const int* __restrict__ sidx,
    const int*   __restrict__ cellstart,
    const float* __restrict__ new_xyz, const int* __restrict__ fps_idx,
    int*         __restrict__ idx_out)
{
    __shared__ int cand[4][CAND_CAP];
    const int w    = threadIdx.x >> 6;
    const int lane = threadIdx.x & 63;
    const int wave = blockIdx.x * 4 + w;     // centroid id, 0..8191
    const int b    = wave >> 11;             // / NPOINT

    const float* cp = new_xyz + (size_t)wave * 3;
    const float cx = cp[0], cy = cp[1], cz = cp[2];
    const float r2 = __fmul_rn(0.1f, 0.1f);

    // Conservative cell ranges (padded radius; clamped).
    int ix0 = (int)floorf((cx - RPADF) * 5.0f); ix0 = ix0 < 0 ? 0 : ix0;
    int ix1 = (int)floorf((cx + RPADF) * 5.0f); ix1 = ix1 > 4 ? 4 : ix1;
    int iy0 = (int)floorf((cy - RPADF) * 5.0f); iy0 = iy0 < 0 ? 0 : iy0;
    int iy1 = (int)floorf((cy + RPADF) * 5.0f); iy1 = iy1 > 4 ? 4 : iy1;
    int iz0 = (int)floorf((cz - RPADF) * 5.0f); iz0 = iz0 < 0 ? 0 : iz0;
    int iz1 = (int)floorf((cz + RPADF) * 5.0f); iz1 = iz1 > 4 ? 4 : iz1;

    const int* cs = cellstart + b * (NCELL + 1);
    const int gb  = b * NN;
    int cnt = 0;

    for (int ix = ix0; ix <= ix1; ++ix) {
        for (int iy = iy0; iy <= iy1; ++iy) {
            const int cbase = (ix * GG + iy) * GG;
            const int st = cs[cbase + iz0];
            const int en = cs[cbase + iz1 + 1];     // z-run is contiguous
            for (int base = st; base < en; base += 64) {
                const int pos = base + lane;
                const bool inb = pos < en;
                const int rp = inb ? pos : st;      // safe clamp (st<en here)
                const float px = sx[gb + rp];
                const float py = sy[gb + rp];
                const float pz = sz[gb + rp];
                const int  oid = sidx[gb + rp];
                const float dx = __fsub_rn(cx, px);
                const float dy = __fsub_rn(cy, py);
                const float dz = __fsub_rn(cz, pz);
                const float d2 = __fadd_rn(__fadd_rn(__fmul_rn(dx, dx), __fmul_rn(dy, dy)),
                                           __fmul_rn(dz, dz));
                const bool valid = inb && (d2 < r2);
                const unsigned long long m = __ballot(valid);
                if (m != 0ull) {                     // wave-uniform branch
                    const int prefix = __builtin_amdgcn_mbcnt_hi(
                        (unsigned)(m >> 32), __builtin_amdgcn_mbcnt_lo((unsigned)m, 0u));
                    const int slot = cnt + prefix;
                    if (valid && slot < CAND_CAP) cand[w][slot] = oid;
                    cnt += (int)__popcll(m);
                }
            }
        }
    }

    const int K = cnt > CAND_CAP ? CAND_CAP : cnt;

    // Rank-select the 32 smallest original indices, output in rank order.
    int v0 = (lane       < K) ? cand[w][lane]       : INT_MAX;
    int v1 = (lane + 64  < K) ? cand[w][lane + 64]  : INT_MAX;
    int v2 = (lane + 128 < K) ? cand[w][lane + 128] : INT_MAX;
    int rk0 = 0, rk1 = 0, rk2 = 0;
    for (int j = 0; j < K; ++j) {
        const int sv = cand[w][j];                  // uniform addr -> broadcast
        rk0 += (sv < v0); rk1 += (sv < v1); rk2 += (sv < v2);
    }
    int* out = idx_out + (size_t)wave * KTOT;
    if (lane       < K && rk0 < NSAMPLE) out[1 + rk0] = v0;
    if (lane + 64  < K && rk1 < NSAMPLE) out[1 + rk1] = v1;
    if (lane + 128 < K && rk2 < NSAMPLE) out[1 + rk2] = v2;

    if (K < NSAMPLE) {                              // pad with min (first hit)
        int mn = v0;                                // K<32<=64 -> min lives in v0
#pragma unroll
        for (int off = 32; off >= 1; off >>= 1) {
            const int o = __shfl_xor(mn, off);
            mn = o < mn ? o : mn;
        }
        const int pad = (K > 0) ? mn : 0;
        if (lane >= K && lane < NSAMPLE) out[1 + lane] = pad;
    }
    if (lane == 0) out[0] = fps_idx[wave];
}

// ---------------------------------------------------------------------------
// Kernel 2a: features (B,C,N) -> ft (B,N,C), LDS-tiled 64x64. (unchanged)
// ---------------------------------------------------------------------------
__global__ __launch_bounds__(256) void feat_transpose(
    const float* __restrict__ f, float* __restrict__ ft)
{
    __shared__ float tile[64 * 65];
    const int blk = blockIdx.x;          // B * (N/64) = 512
    const int b   = blk >> 7;
    const int n0  = (blk & 127) << 6;
    const int w   = threadIdx.x >> 6, l = threadIdx.x & 63;
#pragma unroll
    for (int i = 0; i < 16; ++i) {
        const int c = i * 4 + w;
        tile[l * 65 + c] = f[((size_t)b * CC + c) * NN + n0 + l];  // coalesced read
    }
    __syncthreads();
#pragma unroll
    for (int i = 0; i < 16; ++i) {
        const int flat = i * 256 + threadIdx.x;                    // n*64 + c
        ft[((size_t)b * NN + n0) * CC + flat] = tile[(flat >> 6) * 65 + (flat & 63)];
    }
}

// ---------------------------------------------------------------------------
// Kernel 2b: gather v3 (unchanged). One thread per (b, j, s): 16 float4 loads
// from ft, 70 coalesced channel stores.
// ---------------------------------------------------------------------------
__global__ __launch_bounds__(256) void gather_v3(
    const float* __restrict__ xyz, const float* __restrict__ new_xyz,
    const float* __restrict__ ft, const int* __restrict__ idx,
    float* __restrict__ out)
{
    const int o = blockIdx.x * 256 + threadIdx.x;
    if (o >= BB * NPOINT * KTOT) return;
    const int s = o % KTOT;
    const int t = o / KTOT;
    const int j = t & (NPOINT - 1);
    const int b = t >> 11;
    const int id = idx[o];

    const size_t chstride = (size_t)NPOINT * KTOT;
    const size_t outb = (size_t)b * NCH * chstride + (size_t)j * KTOT + s;

    const float* gp = xyz + ((size_t)b * NN + id) * 3;
    const float* cp = new_xyz + ((size_t)b * NPOINT + j) * 3;
    const float vx = __fsub_rn(gp[0], cp[0]);
    const float vy = __fsub_rn(gp[1], cp[1]);
    const float vz = __fsub_rn(gp[2], cp[2]);
    out[outb]                = vx;
    out[outb + chstride]     = vy;
    out[outb + 2 * chstride] = vz;
    out[outb + 3 * chstride] = vx;
    out[outb + 4 * chstride] = vy;
    out[outb + 5 * chstride] = vz;

    const float4* fp = (const float4*)ft + ((size_t)b * NN + id) * (CC / 4);
#pragma unroll
    for (int q = 0; q < CC / 4; ++q) {
        const float4 v = fp[q];
        const size_t base = outb + (size_t)(6 + 4 * q) * chstride;
        out[base]                = v.x;
        out[base + chstride]     = v.y;
        out[base + 2 * chstride] = v.z;
        out[base + 3 * chstride] = v.w;
    }
}

// ---------------------------------------------------------------------------
// Fallbacks (ws too small — not expected; observed ws >= 10 MB).
// ---------------------------------------------------------------------------
__global__ __launch_bounds__(256) void ball_query_bf(
    const float* __restrict__ xyz, const float* __restrict__ new_xyz,
    const int* __restrict__ fps_idx, int* __restrict__ idx_out)
{
    const int wave = (blockIdx.x * blockDim.x + threadIdx.x) >> 6;
    const int lane = threadIdx.x & 63;
    if (wave >= BB * NPOINT) return;
    const int b = wave >> 11;
    const float* cp = new_xyz + (size_t)wave * 3;
    const float cx = cp[0], cy = cp[1], cz = cp[2];
    const float r2 = __fmul_rn(0.1f, 0.1f);
    const float* xb = xyz + (size_t)b * NN * 3;
    int* out = idx_out + (size_t)wave * KTOT;
    int count = 0, first = 0;
    for (int base = 0; base < NN; base += 64) {
        const int p = base + lane;
        const float dx = __fsub_rn(cx, xb[p * 3 + 0]);
        const float dy = __fsub_rn(cy, xb[p * 3 + 1]);
        const float dz = __fsub_rn(cz, xb[p * 3 + 2]);
        const float d2 = __fadd_rn(__fadd_rn(__fmul_rn(dx, dx), __fmul_rn(dy, dy)),
                                   __fmul_rn(dz, dz));
        const bool valid = d2 < r2;
        const unsigned long long m = __ballot(valid);
        if (count == 0 && m != 0ull) first = base + __builtin_ctzll(m);
        const int prefix = __builtin_amdgcn_mbcnt_hi(
            (unsigned)(m >> 32), __builtin_amdgcn_mbcnt_lo((unsigned)m, 0u));
        const int slot = count + prefix;
        if (valid && slot < NSAMPLE) out[1 + slot] = p;
        count += (int)__popcll(m);
        if (count >= NSAMPLE) break;
    }
    if (count < NSAMPLE) {
        const int pad = (count > 0) ? first : 0;
        if (lane >= count && lane < NSAMPLE) out[1 + lane] = pad;
    }
    if (lane == 0) out[0] = fps_idx[wave];
}

__global__ __launch_bounds__(256) void gather_kernel(
    const float* __restrict__ xyz, const float* __restrict__ new_xyz,
    const float* __restrict__ features, const int* __restrict__ idx,
    float* __restrict__ out)
{
    const long long total = (long long)BB * NCH * NPOINT * KTOT;
    const long long o = (long long)blockIdx.x * blockDim.x + threadIdx.x;
    if (o >= total) return;
    const int s  = (int)(o % KTOT);
    long long t  = o / KTOT;
    const int j  = (int)(t % NPOINT);
    t /= NPOINT;
    const int ch = (int)(t % NCH);
    const int b  = (int)(t / NCH);
    const int id = idx[(long long)(b * NPOINT + j) * KTOT + s];
    float v;
    if (ch < 6) {
        const int c3 = (ch >= 3) ? (ch - 3) : ch;
        v = __fsub_rn(xyz[((long long)b * NN + id) * 3 + c3],
                      new_xyz[((long long)b * NPOINT + j) * 3 + c3]);
    } else {
        v = features[((long long)b * CC + (ch - 6)) * NN + id];
    }
    out[o] = v;
}

extern "C" void kernel_launch(void* const* d_in, const int* in_sizes, int n_in,
                              void* d_out, int out_size, void* d_ws, size_t ws_size,
                              hipStream_t stream) {
    const float* xyz      = (const float*)d_in[0];
    const float* new_xyz  = (const float*)d_in[1];
    const float* features = (const float*)d_in[2];
    const int*   fps_idx  = (const int*)d_in[3];
    float*       out      = (float*)d_out;

    // Workspace layout (16B-aligned offsets).
    const size_t off_idx   = 0;
    const size_t sz_idx    = (size_t)BB * NPOINT * KTOT * 4;  // 1,081,344
    const size_t off_ft    = off_idx + sz_idx;
    const size_t sz_ft     = (size_t)BB * NN * CC * 4;        // 8,388,608
    const size_t off_sx    = off_ft + sz_ft;
    const size_t sz_plane  = (size_t)BB * NN * 4;             // 131,072
    const size_t off_sy    = off_sx + sz_plane;
    const size_t off_sz    = off_sy + sz_plane;
    const size_t off_sidx  = off_sz + sz_plane;
    const size_t off_cnt   = off_sidx + sz_plane;             // cellcnt 4*125 ints
    const size_t sz_cnt    = (size_t)BB * NCELL * 4;          // 2000
    const size_t off_cur   = off_cnt + sz_cnt;                // cursor 4*125 ints
    const size_t off_cs    = off_cur + sz_cnt;                // cellstart 4*126 ints
    const size_t sz_cs     = (size_t)BB * (NCELL + 1) * 4;    // 2016
    const size_t need_full = off_cs + sz_cs;                  // ~10.0 MB

    int* idxbuf = (int*)((char*)d_ws + off_idx);
    const int gblocks = (BB * NPOINT * KTOT + 255) / 256;
    const int pblocks = (BB * NN) / 256;                      // 128

    if (ws_size >= need_full) {
        float* ft   = (float*)((char*)d_ws + off_ft);
        float* sx   = (float*)((char*)d_ws + off_sx);
        float* sy   = (float*)((char*)d_ws + off_sy);
        float* szp  = (float*)((char*)d_ws + off_sz);
        int*   sidx = (int*)  ((char*)d_ws + off_sidx);
        int*   ccnt = (int*)  ((char*)d_ws + off_cnt);
        int*   cur  = (int*)  ((char*)d_ws + off_cur);
        int*   cs   = (int*)  ((char*)d_ws + off_cs);

        // Grid build: zero counters, histogram, scan, scatter.
        (void)hipMemsetAsync(ccnt, 0, 2 * sz_cnt, stream);    // cellcnt + cursor
        hist_kernel<<<pblocks, 256, 0, stream>>>(xyz, ccnt);
        scan_kernel<<<1, 256, 0, stream>>>(ccnt, cs);
        scatter_kernel<<<pblocks, 256, 0, stream>>>(xyz, cs, cur, sx, sy, szp, sidx);

        // Ball query over grid cells. One wave per centroid, 4 waves/block.
        ball_query_grid<<<BB * NPOINT / 4, 256, 0, stream>>>(
            sx, sy, szp, sidx, cs, new_xyz, fps_idx, idxbuf);

        // Gather.
        feat_transpose<<<BB * (NN / 64), 256, 0, stream>>>(features, ft);
        gather_v3<<<gblocks, 256, 0, stream>>>(xyz, new_xyz, ft, idxbuf, out);
    } else if (ws_size >= sz_idx) {
        ball_query_bf<<<BB * NPOINT / 4, 256, 0, stream>>>(xyz, new_xyz, fps_idx, idxbuf);
        const long long total = (long long)BB * NCH * NPOINT * KTOT;
        gather_kernel<<<(int)((total + 255) / 256), 256, 0, stream>>>(
            xyz, new_xyz, features, idxbuf, out);
    }
}

// Round 7
// 133.851 us; speedup vs baseline: 1.0822x; 1.0822x over previous
//
#include <hip/hip_runtime.h>
#include <stdint.h>
#include <limits.h>

// Problem constants (match reference)
constexpr int BB      = 4;
constexpr int NN      = 8192;
constexpr int NPOINT  = 2048;
constexpr int CC      = 64;
constexpr int NSAMPLE = 32;
constexpr int KTOT    = NSAMPLE + 1;   // fps_idx prepended -> 33
constexpr int NCH     = 3 + 3 + CC;    // 70 output channels
constexpr int CHS     = NPOINT * KTOT; // channel stride in out = 67584

// Spatial grid: 5x5x5 cells of 0.2 over [0,1]^3.
constexpr int   GG     = 5;
constexpr int   NCELL  = GG * GG * GG;        // 125
constexpr float RPADF  = 0.1001f;             // conservative cell-range radius
constexpr int   CAND_CAP = 192;               // in-ball ~Poisson(34); +27 sigma

__device__ __forceinline__ int cell_of(float x, float y, float z) {
    int ix = (int)floorf(x * 5.0f); ix = ix < 0 ? 0 : (ix > 4 ? 4 : ix);
    int iy = (int)floorf(y * 5.0f); iy = iy < 0 ? 0 : (iy > 4 ? 4 : iy);
    int iz = (int)floorf(z * 5.0f); iz = iz < 0 ? 0 : (iz > 4 ? 4 : iz);
    return (ix * GG + iy) * GG + iz;
}

// ---------------------------------------------------------------------------
// Kernel A: per-batch LDS histogram + scan. One 1024-thread block per batch.
// Writes cellstart[b][126] and seeds cursor[b][125] = cellstart (so scatter
// needs no memset and no separate scan kernel). Replaces memset+hist+scan.
// ---------------------------------------------------------------------------
__global__ __launch_bounds__(1024) void grid_hist_scan(
    const float* __restrict__ xyz, int* __restrict__ cellstartg,
    int* __restrict__ cursorg)
{
    __shared__ int hist[NCELL];
    __shared__ int csl[NCELL + 1];
    const int b = blockIdx.x;
    const int t = threadIdx.x;
    if (t < NCELL) hist[t] = 0;
    __syncthreads();
    const float* xb = xyz + (size_t)b * NN * 3;
#pragma unroll
    for (int k = 0; k < NN / 1024; ++k) {
        const float* p = xb + (size_t)(t + k * 1024) * 3;
        atomicAdd(&hist[cell_of(p[0], p[1], p[2])], 1);
    }
    __syncthreads();
    if (t < 64) {                         // wave 0: scan 125 counts
        int x0 = hist[t];
        int x1 = (t + 64 < NCELL) ? hist[t + 64] : 0;
#pragma unroll
        for (int d = 1; d < 64; d <<= 1) {
            int t0 = __shfl_up(x0, d);
            int t1 = __shfl_up(x1, d);
            if (t >= d) { x0 += t0; x1 += t1; }
        }
        x1 += __shfl(x0, 63);
        if (t == 0) csl[0] = 0;
        csl[1 + t] = x0;
        if (t <= 60) csl[65 + t] = x1;
    }
    __syncthreads();
    if (t < NCELL + 1) cellstartg[b * (NCELL + 1) + t] = csl[t];
    if (t < NCELL)     cursorg[b * NCELL + t]          = csl[t];
}

// ---------------------------------------------------------------------------
// Kernel B: scatter points into cell-sorted AoS float4 (x,y,z,bitcast(idx)).
// One 16B store per point (vs 4 scalar stores before). Order within a cell is
// arbitrary — rank-select in ball_query_grid restores index order.
// ---------------------------------------------------------------------------
__global__ __launch_bounds__(256) void scatter_aos(
    const float* __restrict__ xyz, int* __restrict__ cursor,
    float4* __restrict__ spt)
{
    const int t = blockIdx.x * 256 + threadIdx.x;
    if (t >= BB * NN) return;
    const int b = t >> 13;
    const int n = t & (NN - 1);
    const float* p = xyz + (size_t)t * 3;
    const float x = p[0], y = p[1], z = p[2];
    const int c = cell_of(x, y, z);
    const int pos = atomicAdd(&cursor[b * NCELL + c], 1);   // seeded w/ cellstart
    spt[b * NN + pos] = make_float4(x, y, z, __int_as_float(n));
}

// ---------------------------------------------------------------------------
// Kernel C: grid ball query. One wave per centroid; walks <=3x3 xy cell
// columns (z-runs contiguous); exact d2 < r2 with the numpy-fp32 __f*_rn
// chain; compacts hits to LDS; rank-select emits first-32-in-index-order;
// pad = min hit (0 if empty); slot 0 = fps_idx.
// ---------------------------------------------------------------------------
__global__ __launch_bounds__(256) void ball_query_grid(
    const float4* __restrict__ spt, const int* __restrict__ cellstart,
    const float* __restrict__ new_xyz, const int* __restrict__ fps_idx,
    int*         __restrict__ idx_out)
{
    __shared__ int cand[4][CAND_CAP];
    const int w    = threadIdx.x >> 6;
    const int lane = threadIdx.x & 63;
    const int wave = blockIdx.x * 4 + w;     // centroid id, 0..8191
    const int b    = wave >> 11;             // / NPOINT

    const float* cp = new_xyz + (size_t)wave * 3;
    const float cx = cp[0], cy = cp[1], cz = cp[2];
    const float r2 = __fmul_rn(0.1f, 0.1f);

    int ix0 = (int)floorf((cx - RPADF) * 5.0f); ix0 = ix0 < 0 ? 0 : ix0;
    int ix1 = (int)floorf((cx + RPADF) * 5.0f); ix1 = ix1 > 4 ? 4 : ix1;
    int iy0 = (int)floorf((cy - RPADF) * 5.0f); iy0 = iy0 < 0 ? 0 : iy0;
    int iy1 = (int)floorf((cy + RPADF) * 5.0f); iy1 = iy1 > 4 ? 4 : iy1;
    int iz0 = (int)floorf((cz - RPADF) * 5.0f); iz0 = iz0 < 0 ? 0 : iz0;
    int iz1 = (int)floorf((cz + RPADF) * 5.0f); iz1 = iz1 > 4 ? 4 : iz1;

    const int* cs = cellstart + b * (NCELL + 1);
    const int gb  = b * NN;
    int cnt = 0;

    for (int ix = ix0; ix <= ix1; ++ix) {
        for (int iy = iy0; iy <= iy1; ++iy) {
            const int cbase = (ix * GG + iy) * GG;
            const int st = cs[cbase + iz0];
            const int en = cs[cbase + iz1 + 1];
            for (int base = st; base < en; base += 64) {
                const int pos = base + lane;
                const bool inb = pos < en;
                const float4 q = spt[gb + (inb ? pos : st)];
                const int oid = __float_as_int(q.w);
                const float dx = __fsub_rn(cx, q.x);
                const float dy = __fsub_rn(cy, q.y);
                const float dz = __fsub_rn(cz, q.z);
                const float d2 = __fadd_rn(__fadd_rn(__fmul_rn(dx, dx), __fmul_rn(dy, dy)),
                                           __fmul_rn(dz, dz));
                const bool valid = inb && (d2 < r2);
                const unsigned long long m = __ballot(valid);
                if (m != 0ull) {
                    const int prefix = __builtin_amdgcn_mbcnt_hi(
                        (unsigned)(m >> 32), __builtin_amdgcn_mbcnt_lo((unsigned)m, 0u));
                    const int slot = cnt + prefix;
                    if (valid && slot < CAND_CAP) cand[w][slot] = oid;
                    cnt += (int)__popcll(m);
                }
            }
        }
    }

    const int K = cnt > CAND_CAP ? CAND_CAP : cnt;

    int v0 = (lane       < K) ? cand[w][lane]       : INT_MAX;
    int v1 = (lane + 64  < K) ? cand[w][lane + 64]  : INT_MAX;
    int v2 = (lane + 128 < K) ? cand[w][lane + 128] : INT_MAX;
    int rk0 = 0, rk1 = 0, rk2 = 0;
    for (int j = 0; j < K; ++j) {
        const int sv = cand[w][j];
        rk0 += (sv < v0); rk1 += (sv < v1); rk2 += (sv < v2);
    }
    int* out = idx_out + (size_t)wave * KTOT;
    if (lane       < K && rk0 < NSAMPLE) out[1 + rk0] = v0;
    if (lane + 64  < K && rk1 < NSAMPLE) out[1 + rk1] = v1;
    if (lane + 128 < K && rk2 < NSAMPLE) out[1 + rk2] = v2;

    if (K < NSAMPLE) {
        int mn = v0;
#pragma unroll
        for (int off = 32; off >= 1; off >>= 1) {
            const int o = __shfl_xor(mn, off);
            mn = o < mn ? o : mn;
        }
        const int pad = (K > 0) ? mn : 0;
        if (lane >= K && lane < NSAMPLE) out[1 + lane] = pad;
    }
    if (lane == 0) out[0] = fps_idx[wave];
}

// ---------------------------------------------------------------------------
// Kernel D: features (B,C,N) -> ft (B,N,C), LDS-tiled 64x64. (unchanged)
// ---------------------------------------------------------------------------
__global__ __launch_bounds__(256) void feat_transpose(
    const float* __restrict__ f, float* __restrict__ ft)
{
    __shared__ float tile[64 * 65];
    const int blk = blockIdx.x;          // B * (N/64) = 512
    const int b   = blk >> 7;
    const int n0  = (blk & 127) << 6;
    const int w   = threadIdx.x >> 6, l = threadIdx.x & 63;
#pragma unroll
    for (int i = 0; i < 16; ++i) {
        const int c = i * 4 + w;
        tile[l * 65 + c] = f[((size_t)b * CC + c) * NN + n0 + l];  // coalesced read
    }
    __syncthreads();
#pragma unroll
    for (int i = 0; i < 16; ++i) {
        const int flat = i * 256 + threadIdx.x;                    // n*64 + c
        ft[((size_t)b * NN + n0) * CC + flat] = tile[(flat >> 6) * 65 + (flat & 63)];
    }
}

// ---------------------------------------------------------------------------
// Kernel E: gather v4 — 4-lane cooperative. Lanes g=0..3 of each group share
// one (b,j,s) slot. Load inst i: lane g reads float4 row[i*4+g] -> the group
// requests one contiguous 64B line => 16 transactions/wave-inst (vs 64 in
// v3). Total load lookups drop 17.3M -> 4.3M (the line floor). Lane g ends
// holding channels 16i+4g+r; stores land as 4 coalesced 64B plane-segments
// per instruction. xyz channels handled by lanes g<3.
// ---------------------------------------------------------------------------
__global__ __launch_bounds__(256) void gather_v4(
    const float* __restrict__ xyz, const float* __restrict__ new_xyz,
    const float4* __restrict__ ft4, const int* __restrict__ idx,
    float* __restrict__ out)
{
    const int gt = blockIdx.x * 256 + threadIdx.x;
    const int o  = gt >> 2;                 // slot index
    const int g  = gt & 3;
    if (o >= BB * CHS) return;
    const int id = idx[o];
    const int b  = o / CHS;
    const int jj = o - b * CHS;             // j*KTOT + s
    const size_t outbase = (size_t)b * NCH * CHS + jj;

    // xyz / centered channels (0..2 and duplicate 3..5)
    if (g < 3) {
        const float pv = xyz[(size_t)(b * NN + id) * 3 + g];
        const float cv = new_xyz[(size_t)(o / KTOT) * 3 + g];
        const float d  = __fsub_rn(pv, cv);
        out[outbase + (size_t)g * CHS]       = d;
        out[outbase + (size_t)(g + 3) * CHS] = d;
    }

    // feature channels: row = 64 floats = 16 float4 = 4 cachelines
    const float4* row = ft4 + ((size_t)b * NN + id) * (CC / 4);
    float4 v[4];
#pragma unroll
    for (int i = 0; i < 4; ++i) v[i] = row[i * 4 + g];
#pragma unroll
    for (int i = 0; i < 4; ++i) {
        const size_t base = outbase + (size_t)(6 + 16 * i + 4 * g) * CHS;
        out[base]           = v[i].x;
        out[base + CHS]     = v[i].y;
        out[base + 2 * CHS] = v[i].z;
        out[base + 3 * CHS] = v[i].w;
    }
}

// ---------------------------------------------------------------------------
// Fallbacks (ws too small — not expected; observed ws ~302 MB).
// ---------------------------------------------------------------------------
__global__ __launch_bounds__(256) void ball_query_bf(
    const float* __restrict__ xyz, const float* __restrict__ new_xyz,
    const int* __restrict__ fps_idx, int* __restrict__ idx_out)
{
    const int wave = (blockIdx.x * blockDim.x + threadIdx.x) >> 6;
    const int lane = threadIdx.x & 63;
    if (wave >= BB * NPOINT) return;
    const int b = wave >> 11;
    const float* cp = new_xyz + (size_t)wave * 3;
    const float cx = cp[0], cy = cp[1], cz = cp[2];
    const float r2 = __fmul_rn(0.1f, 0.1f);
    const float* xb = xyz + (size_t)b * NN * 3;
    int* out = idx_out + (size_t)wave * KTOT;
    int count = 0, first = 0;
    for (int base = 0; base < NN; base += 64) {
        const int p = base + lane;
        const float dx = __fsub_rn(cx, xb[p * 3 + 0]);
        const float dy = __fsub_rn(cy, xb[p * 3 + 1]);
        const float dz = __fsub_rn(cz, xb[p * 3 + 2]);
        const float d2 = __fadd_rn(__fadd_rn(__fmul_rn(dx, dx), __fmul_rn(dy, dy)),
                                   __fmul_rn(dz, dz));
        const bool valid = d2 < r2;
        const unsigned long long m = __ballot(valid);
        if (count == 0 && m != 0ull) first = base + __builtin_ctzll(m);
        const int prefix = __builtin_amdgcn_mbcnt_hi(
            (unsigned)(m >> 32), __builtin_amdgcn_mbcnt_lo((unsigned)m, 0u));
        const int slot = count + prefix;
        if (valid && slot < NSAMPLE) out[1 + slot] = p;
        count += (int)__popcll(m);
        if (count >= NSAMPLE) break;
    }
    if (count < NSAMPLE) {
        const int pad = (count > 0) ? first : 0;
        if (lane >= count && lane < NSAMPLE) out[1 + lane] = pad;
    }
    if (lane == 0) out[0] = fps_idx[wave];
}

__global__ __launch_bounds__(256) void gather_kernel(
    const float* __restrict__ xyz, const float* __restrict__ new_xyz,
    const float* __restrict__ features, const int* __restrict__ idx,
    float* __restrict__ out)
{
    const long long total = (long long)BB * NCH * CHS;
    const long long o = (long long)blockIdx.x * blockDim.x + threadIdx.x;
    if (o >= total) return;
    const int s  = (int)(o % KTOT);
    long long t  = o / KTOT;
    const int j  = (int)(t % NPOINT);
    t /= NPOINT;
    const int ch = (int)(t % NCH);
    const int b  = (int)(t / NCH);
    const int id = idx[(long long)(b * NPOINT + j) * KTOT + s];
    float v;
    if (ch < 6) {
        const int c3 = (ch >= 3) ? (ch - 3) : ch;
        v = __fsub_rn(xyz[((long long)b * NN + id) * 3 + c3],
                      new_xyz[((long long)b * NPOINT + j) * 3 + c3]);
    } else {
        v = features[((long long)b * CC + (ch - 6)) * NN + id];
    }
    out[o] = v;
}

extern "C" void kernel_launch(void* const* d_in, const int* in_sizes, int n_in,
                              void* d_out, int out_size, void* d_ws, size_t ws_size,
                              hipStream_t stream) {
    const float* xyz      = (const float*)d_in[0];
    const float* new_xyz  = (const float*)d_in[1];
    const float* features = (const float*)d_in[2];
    const int*   fps_idx  = (const int*)d_in[3];
    float*       out      = (float*)d_out;

    // Workspace layout (16B-aligned offsets).
    const size_t off_idx  = 0;
    const size_t sz_idx   = (size_t)BB * CHS * 4;            // 1,081,344
    const size_t off_ft   = off_idx + sz_idx;
    const size_t sz_ft    = (size_t)BB * NN * CC * 4;        // 8,388,608
    const size_t off_spt  = off_ft + sz_ft;
    const size_t sz_spt   = (size_t)BB * NN * 16;            // 524,288
    const size_t off_cs   = off_spt + sz_spt;
    const size_t sz_cs    = (size_t)BB * (NCELL + 1) * 4;    // 2016 -> pad
    const size_t off_cur  = off_cs + 2048;
    const size_t need_full = off_cur + 2048;                 // ~10.0 MB

    int* idxbuf = (int*)((char*)d_ws + off_idx);
    const int gblocks4 = (BB * CHS * 4 + 255) / 256;         // 16,896

    if (ws_size >= need_full) {
        float*  ft   = (float*) ((char*)d_ws + off_ft);
        float4* spt  = (float4*)((char*)d_ws + off_spt);
        int*    cs   = (int*)   ((char*)d_ws + off_cs);
        int*    cur  = (int*)   ((char*)d_ws + off_cur);

        // Grid build: fused hist+scan (seeds cursors), then AoS scatter.
        grid_hist_scan<<<BB, 1024, 0, stream>>>(xyz, cs, cur);
        scatter_aos<<<(BB * NN) / 256, 256, 0, stream>>>(xyz, cur, spt);

        // Ball query over grid cells. One wave per centroid, 4 waves/block.
        ball_query_grid<<<BB * NPOINT / 4, 256, 0, stream>>>(
            spt, cs, new_xyz, fps_idx, idxbuf);

        // Gather: transpose features, then 4-lane cooperative gather.
        feat_transpose<<<BB * (NN / 64), 256, 0, stream>>>(features, ft);
        gather_v4<<<gblocks4, 256, 0, stream>>>(xyz, new_xyz, (const float4*)ft,
                                                idxbuf, out);
    } else if (ws_size >= sz_idx) {
        ball_query_bf<<<BB * NPOINT / 4, 256, 0, stream>>>(xyz, new_xyz, fps_idx, idxbuf);
        const long long total = (long long)BB * NCH * CHS;
        gather_kernel<<<(int)((total + 255) / 256), 256, 0, stream>>>(
            xyz, new_xyz, features, idxbuf, out);
    }
}

// Round 8
// 124.110 us; speedup vs baseline: 1.1671x; 1.0785x over previous
//
#include <hip/hip_runtime.h>
#include <stdint.h>
#include <limits.h>

// Problem constants (match reference)
constexpr int BB      = 4;
constexpr int NN      = 8192;
constexpr int NPOINT  = 2048;
constexpr int CC      = 64;
constexpr int NSAMPLE = 32;
constexpr int KTOT    = NSAMPLE + 1;   // fps_idx prepended -> 33
constexpr int NCH     = 3 + 3 + CC;    // 70 output channels
constexpr int CHS     = NPOINT * KTOT; // channel stride in out = 67584

// Spatial grid: 5x5x5 cells of 0.2 over [0,1]^3.
constexpr int   GG     = 5;
constexpr int   NCELL  = GG * GG * GG;        // 125
constexpr float RPADF  = 0.1001f;             // conservative cell-range radius
constexpr int   CAND_CAP = 192;               // in-ball ~Poisson(34); +27 sigma

__device__ __forceinline__ int cell_of(float x, float y, float z) {
    int ix = (int)floorf(x * 5.0f); ix = ix < 0 ? 0 : (ix > 4 ? 4 : ix);
    int iy = (int)floorf(y * 5.0f); iy = iy < 0 ? 0 : (iy > 4 ? 4 : iy);
    int iz = (int)floorf(z * 5.0f); iz = iz < 0 ? 0 : (iz > 4 ? 4 : iz);
    return (ix * GG + iy) * GG + iz;
}

// ---------------------------------------------------------------------------
// Kernel A: fused grid build. One 1024-thread block per batch: LDS histogram,
// wave-0 scan, LDS-cursor scatter into cell-sorted AoS float4
// (x,y,z,bitcast(origidx)). Points cached in registers between phases.
// ---------------------------------------------------------------------------
__global__ __launch_bounds__(1024) void grid_build(
    const float* __restrict__ xyz, int* __restrict__ cellstartg,
    float4* __restrict__ spt)
{
    __shared__ int hist[NCELL];
    __shared__ int csl[NCELL + 1];
    __shared__ int cur[NCELL];
    const int b = blockIdx.x;
    const int t = threadIdx.x;
    if (t < NCELL) hist[t] = 0;
    __syncthreads();
    const float* xb = xyz + (size_t)b * NN * 3;
    float px[NN / 1024], py[NN / 1024], pz[NN / 1024];
    int   pc[NN / 1024];
#pragma unroll
    for (int k = 0; k < NN / 1024; ++k) {
        const float* p = xb + (size_t)(t + k * 1024) * 3;
        px[k] = p[0]; py[k] = p[1]; pz[k] = p[2];
        pc[k] = cell_of(px[k], py[k], pz[k]);
        atomicAdd(&hist[pc[k]], 1);
    }
    __syncthreads();
    if (t < 64) {                         // wave 0: scan 125 counts
        int x0 = hist[t];
        int x1 = (t + 64 < NCELL) ? hist[t + 64] : 0;
#pragma unroll
        for (int d = 1; d < 64; d <<= 1) {
            int t0 = __shfl_up(x0, d);
            int t1 = __shfl_up(x1, d);
            if (t >= d) { x0 += t0; x1 += t1; }
        }
        x1 += __shfl(x0, 63);
        if (t == 0) csl[0] = 0;
        csl[1 + t] = x0;
        if (t <= 60) csl[65 + t] = x1;
    }
    __syncthreads();
    if (t < NCELL + 1) cellstartg[b * (NCELL + 1) + t] = csl[t];
    if (t < NCELL)     cur[t] = csl[t];
    __syncthreads();
#pragma unroll
    for (int k = 0; k < NN / 1024; ++k) {
        const int pos = atomicAdd(&cur[pc[k]], 1);
        spt[b * NN + pos] = make_float4(px[k], py[k], pz[k],
                                        __int_as_float(t + k * 1024));
    }
}

// ---------------------------------------------------------------------------
// Kernel B: grid ball query (unchanged from round 7 — ~7 us). One wave per
// centroid; exact d2 < r2 via the numpy-fp32 __f*_rn chain; rank-select
// emits first-32-in-index-order; pad = min hit; slot 0 = fps_idx.
// ---------------------------------------------------------------------------
__global__ __launch_bounds__(256) void ball_query_grid(
    const float4* __restrict__ spt, const int* __restrict__ cellstart,
    const float* __restrict__ new_xyz, const int* __restrict__ fps_idx,
    int*         __restrict__ idx_out)
{
    __shared__ int cand[4][CAND_CAP];
    const int w    = threadIdx.x >> 6;
    const int lane = threadIdx.x & 63;
    const int wave = blockIdx.x * 4 + w;     // centroid id, 0..8191
    const int b    = wave >> 11;             // / NPOINT

    const float* cp = new_xyz + (size_t)wave * 3;
    const float cx = cp[0], cy = cp[1], cz = cp[2];
    const float r2 = __fmul_rn(0.1f, 0.1f);

    int ix0 = (int)floorf((cx - RPADF) * 5.0f); ix0 = ix0 < 0 ? 0 : ix0;
    int ix1 = (int)floorf((cx + RPADF) * 5.0f); ix1 = ix1 > 4 ? 4 : ix1;
    int iy0 = (int)floorf((cy - RPADF) * 5.0f); iy0 = iy0 < 0 ? 0 : iy0;
    int iy1 = (int)floorf((cy + RPADF) * 5.0f); iy1 = iy1 > 4 ? 4 : iy1;
    int iz0 = (int)floorf((cz - RPADF) * 5.0f); iz0 = iz0 < 0 ? 0 : iz0;
    int iz1 = (int)floorf((cz + RPADF) * 5.0f); iz1 = iz1 > 4 ? 4 : iz1;

    const int* cs = cellstart + b * (NCELL + 1);
    const int gb  = b * NN;
    int cnt = 0;

    for (int ix = ix0; ix <= ix1; ++ix) {
        for (int iy = iy0; iy <= iy1; ++iy) {
            const int cbase = (ix * GG + iy) * GG;
            const int st = cs[cbase + iz0];
            const int en = cs[cbase + iz1 + 1];
            for (int base = st; base < en; base += 64) {
                const int pos = base + lane;
                const bool inb = pos < en;
                const float4 q = spt[gb + (inb ? pos : st)];
                const int oid = __float_as_int(q.w);
                const float dx = __fsub_rn(cx, q.x);
                const float dy = __fsub_rn(cy, q.y);
                const float dz = __fsub_rn(cz, q.z);
                const float d2 = __fadd_rn(__fadd_rn(__fmul_rn(dx, dx), __fmul_rn(dy, dy)),
                                           __fmul_rn(dz, dz));
                const bool valid = inb && (d2 < r2);
                const unsigned long long m = __ballot(valid);
                if (m != 0ull) {
                    const int prefix = __builtin_amdgcn_mbcnt_hi(
                        (unsigned)(m >> 32), __builtin_amdgcn_mbcnt_lo((unsigned)m, 0u));
                    const int slot = cnt + prefix;
                    if (valid && slot < CAND_CAP) cand[w][slot] = oid;
                    cnt += (int)__popcll(m);
                }
            }
        }
    }

    const int K = cnt > CAND_CAP ? CAND_CAP : cnt;

    int v0 = (lane       < K) ? cand[w][lane]       : INT_MAX;
    int v1 = (lane + 64  < K) ? cand[w][lane + 64]  : INT_MAX;
    int v2 = (lane + 128 < K) ? cand[w][lane + 128] : INT_MAX;
    int rk0 = 0, rk1 = 0, rk2 = 0;
    for (int j = 0; j < K; ++j) {
        const int sv = cand[w][j];
        rk0 += (sv < v0); rk1 += (sv < v1); rk2 += (sv < v2);
    }
    int* out = idx_out + (size_t)wave * KTOT;
    if (lane       < K && rk0 < NSAMPLE) out[1 + rk0] = v0;
    if (lane + 64  < K && rk1 < NSAMPLE) out[1 + rk1] = v1;
    if (lane + 128 < K && rk2 < NSAMPLE) out[1 + rk2] = v2;

    if (K < NSAMPLE) {
        int mn = v0;
#pragma unroll
        for (int off = 32; off >= 1; off >>= 1) {
            const int o = __shfl_xor(mn, off);
            mn = o < mn ? o : mn;
        }
        const int pad = (K > 0) ? mn : 0;
        if (lane >= K && lane < NSAMPLE) out[1 + lane] = pad;
    }
    if (lane == 0) out[0] = fps_idx[wave];
}

// ---------------------------------------------------------------------------
// Kernel C: features (B,C,N) -> ft (B,N,C), LDS-tiled 64x64. (unchanged)
// ---------------------------------------------------------------------------
__global__ __launch_bounds__(256) void feat_transpose(
    const float* __restrict__ f, float* __restrict__ ft)
{
    __shared__ float tile[64 * 65];
    const int blk = blockIdx.x;          // B * (N/64) = 512
    const int b   = blk >> 7;
    const int n0  = (blk & 127) << 6;
    const int w   = threadIdx.x >> 6, l = threadIdx.x & 63;
#pragma unroll
    for (int i = 0; i < 16; ++i) {
        const int c = i * 4 + w;
        tile[l * 65 + c] = f[((size_t)b * CC + c) * NN + n0 + l];  // coalesced read
    }
    __syncthreads();
#pragma unroll
    for (int i = 0; i < 16; ++i) {
        const int flat = i * 256 + threadIdx.x;                    // n*64 + c
        ft[((size_t)b * NN + n0) * CC + flat] = tile[(flat >> 6) * 65 + (flat & 63)];
    }
}

// ---------------------------------------------------------------------------
// Kernel D: gather v7 — LDS-decoupled. Block = 256 threads per 64 slots.
// Phase A: centered xyz -> tile ch 0..5. Phase B: feature rows loaded with
// 4 independent float4 insts per thread (NO interleaved global stores ->
// full MLP), written channel-major to LDS (stride 66 -> <=2-way banks = free).
// Phase C: pure store stream — per wave-inst one channel plane x 64
// consecutive floats, zero load dependencies.
// v3/v4 failed because each thread serialized load->store->load (~16 memory
// round-trips, VGPR_Count=8 rolling buffer); the barrier splits that chain.
// ---------------------------------------------------------------------------
constexpr int TPAD = 66;   // tile stride: bank = (2*ch + col) % 32 -> 2-way max
__global__ __launch_bounds__(256) void gather_v7(
    const float* __restrict__ xyz, const float* __restrict__ new_xyz,
    const float4* __restrict__ ft4, const int* __restrict__ idx,
    float* __restrict__ out)
{
    __shared__ float tile[NCH][TPAD];    // 70 x 66 x 4B = 18.5 KB
    const int blk = blockIdx.x;          // 4224 blocks
    const int t   = threadIdx.x;
    const int jj0 = blk * 64;            // global slot base; CHS % 64 == 0
    const int b   = jj0 / CHS;
    const int jjb = jj0 - b * CHS;       // slot base within batch

    // Phase A: slot ids + centered xyz channels 0..5 (threads 0..63).
    if (t < 64) {
        const int id = idx[jj0 + t];
        const int j  = (jjb + t) / KTOT;
        const float* gp = xyz + (size_t)(b * NN + id) * 3;
        const float* cp = new_xyz + (size_t)(b * NPOINT + j) * 3;
        const float vx = __fsub_rn(gp[0], cp[0]);
        const float vy = __fsub_rn(gp[1], cp[1]);
        const float vz = __fsub_rn(gp[2], cp[2]);
        tile[0][t] = vx; tile[1][t] = vy; tile[2][t] = vz;
        tile[3][t] = vx; tile[4][t] = vy; tile[5][t] = vz;
    }

    // Phase B: feature rows -> LDS, channel-major. Thread group of 4 lanes
    // (g=0..3) covers row r's 16 float4s; load inst i reads row[4i+g] so each
    // group requests one contiguous 64B line; all 4 loads independent.
    {
        const int r = t >> 2, g = t & 3;
        const int id = idx[jj0 + r];                    // 4 lanes same addr (L1)
        const float4* row = ft4 + ((size_t)b * NN + id) * (CC / 4);
        float4 v[4];
#pragma unroll
        for (int i = 0; i < 4; ++i) v[i] = row[4 * i + g];
#pragma unroll
        for (int i = 0; i < 4; ++i) {
            const int c0 = 6 + 16 * i + 4 * g;          // channels of row[4i+g]
            tile[c0 + 0][r] = v[i].x;
            tile[c0 + 1][r] = v[i].y;
            tile[c0 + 2][r] = v[i].z;
            tile[c0 + 3][r] = v[i].w;
        }
    }
    __syncthreads();

    // Phase C: stream 70 planes x 64 consecutive positions. Wave w handles
    // plane 4k+w -> per wave-inst: one plane, 256B coalesced store.
    const int w   = t >> 6;
    const int col = t & 63;
    const size_t ob = (size_t)b * NCH * CHS + (size_t)jjb + col;
#pragma unroll
    for (int k = 0; k < 18; ++k) {
        const int ch = 4 * k + w;
        if (ch < NCH) out[ob + (size_t)ch * CHS] = tile[ch][col];
    }
}

// ---------------------------------------------------------------------------
// Fallbacks (ws too small — not expected; observed ws ~302 MB).
// ---------------------------------------------------------------------------
__global__ __launch_bounds__(256) void ball_query_bf(
    const float* __restrict__ xyz, const float* __restrict__ new_xyz,
    const int* __restrict__ fps_idx, int* __restrict__ idx_out)
{
    const int wave = (blockIdx.x * blockDim.x + threadIdx.x) >> 6;
    const int lane = threadIdx.x & 63;
    if (wave >= BB * NPOINT) return;
    const int b = wave >> 11;
    const float* cp = new_xyz + (size_t)wave * 3;
    const float cx = cp[0], cy = cp[1], cz = cp[2];
    const float r2 = __fmul_rn(0.1f, 0.1f);
    const float* xb = xyz + (size_t)b * NN * 3;
    int* out = idx_out + (size_t)wave * KTOT;
    int count = 0, first = 0;
    for (int base = 0; base < NN; base += 64) {
        const int p = base + lane;
        const float dx = __fsub_rn(cx, xb[p * 3 + 0]);
        const float dy = __fsub_rn(cy, xb[p * 3 + 1]);
        const float dz = __fsub_rn(cz, xb[p * 3 + 2]);
        const float d2 = __fadd_rn(__fadd_rn(__fmul_rn(dx, dx), __fmul_rn(dy, dy)),
                                   __fmul_rn(dz, dz));
        const bool valid = d2 < r2;
        const unsigned long long m = __ballot(valid);
        if (count == 0 && m != 0ull) first = base + __builtin_ctzll(m);
        const int prefix = __builtin_amdgcn_mbcnt_hi(
            (unsigned)(m >> 32), __builtin_amdgcn_mbcnt_lo((unsigned)m, 0u));
        const int slot = count + prefix;
        if (valid && slot < NSAMPLE) out[1 + slot] = p;
        count += (int)__popcll(m);
        if (count >= NSAMPLE) break;
    }
    if (count < NSAMPLE) {
        const int pad = (count > 0) ? first : 0;
        if (lane >= count && lane < NSAMPLE) out[1 + lane] = pad;
    }
    if (lane == 0) out[0] = fps_idx[wave];
}

__global__ __launch_bounds__(256) void gather_kernel(
    const float* __restrict__ xyz, const float* __restrict__ new_xyz,
    const float* __restrict__ features, const int* __restrict__ idx,
    float* __restrict__ out)
{
    const long long total = (long long)BB * NCH * CHS;
    const long long o = (long long)blockIdx.x * blockDim.x + threadIdx.x;
    if (o >= total) return;
    const int s  = (int)(o % KTOT);
    long long t  = o / KTOT;
    const int j  = (int)(t % NPOINT);
    t /= NPOINT;
    const int ch = (int)(t % NCH);
    const int b  = (int)(t / NCH);
    const int id = idx[(long long)(b * NPOINT + j) * KTOT + s];
    float v;
    if (ch < 6) {
        const int c3 = (ch >= 3) ? (ch - 3) : ch;
        v = __fsub_rn(xyz[((long long)b * NN + id) * 3 + c3],
                      new_xyz[((long long)b * NPOINT + j) * 3 + c3]);
    } else {
        v = features[((long long)b * CC + (ch - 6)) * NN + id];
    }
    out[o] = v;
}

extern "C" void kernel_launch(void* const* d_in, const int* in_sizes, int n_in,
                              void* d_out, int out_size, void* d_ws, size_t ws_size,
                              hipStream_t stream) {
    const float* xyz      = (const float*)d_in[0];
    const float* new_xyz  = (const float*)d_in[1];
    const float* features = (const float*)d_in[2];
    const int*   fps_idx  = (const int*)d_in[3];
    float*       out      = (float*)d_out;

    // Workspace layout (16B-aligned offsets).
    const size_t off_idx  = 0;
    const size_t sz_idx   = (size_t)BB * CHS * 4;            // 1,081,344
    const size_t off_ft   = off_idx + sz_idx;
    const size_t sz_ft    = (size_t)BB * NN * CC * 4;        // 8,388,608
    const size_t off_spt  = off_ft + sz_ft;
    const size_t sz_spt   = (size_t)BB * NN * 16;            // 524,288
    const size_t off_cs   = off_spt + sz_spt;
    const size_t need_full = off_cs + 2048;                  // ~10.0 MB

    int* idxbuf = (int*)((char*)d_ws + off_idx);

    if (ws_size >= need_full) {
        float*  ft  = (float*) ((char*)d_ws + off_ft);
        float4* spt = (float4*)((char*)d_ws + off_spt);
        int*    cs  = (int*)   ((char*)d_ws + off_cs);

        // Grid build (fused hist+scan+scatter, one block per batch).
        grid_build<<<BB, 1024, 0, stream>>>(xyz, cs, spt);

        // Ball query over grid cells. One wave per centroid, 4 waves/block.
        ball_query_grid<<<BB * NPOINT / 4, 256, 0, stream>>>(
            spt, cs, new_xyz, fps_idx, idxbuf);

        // Gather: transpose features, then LDS-decoupled gather.
        feat_transpose<<<BB * (NN / 64), 256, 0, stream>>>(features, ft);
        gather_v7<<<BB * CHS / 64, 256, 0, stream>>>(xyz, new_xyz, (const float4*)ft,
                                                     idxbuf, out);
    } else if (ws_size >= sz_idx) {
        ball_query_bf<<<BB * NPOINT / 4, 256, 0, stream>>>(xyz, new_xyz, fps_idx, idxbuf);
        const long long total = (long long)BB * NCH * CHS;
        gather_kernel<<<(int)((total + 255) / 256), 256, 0, stream>>>(
            xyz, new_xyz, features, idxbuf, out);
    }
}